// Round 11
// baseline (715.470 us; speedup 1.0000x reference)
//
#include <hip/hip_runtime.h>

#define N_GRAPHS 64
#define IN_FEATS 64
#define HIDDEN 32
#define GCH 256

// ---------------- K0: init ----------------
// graph bounds, ge zero, done zero, M = W1@W2@W3 [64,2], c1 = b1@W2@W3, c2 = b2@W3
__global__ __launch_bounds__(256) void k_init(const int* __restrict__ gids, int n,
                                              int* __restrict__ gstart,
                                              float* __restrict__ ge,
                                              int* __restrict__ done,
                                              const float* __restrict__ W1,
                                              const float* __restrict__ b1,
                                              const float* __restrict__ W2,
                                              const float* __restrict__ b2,
                                              const float* __restrict__ W3,
                                              float* __restrict__ Mg,
                                              float* __restrict__ cc) {
    __shared__ float w23[HIDDEN * 2];
    int tid = threadIdx.x;
    for (int i = tid; i < N_GRAPHS * IN_FEATS; i += 256) ge[i] = 0.f;
    if (tid < 2) done[tid] = 0;
    if (tid <= N_GRAPHS) {
        int g = tid;
        int lo = 0, hi = n;
        while (lo < hi) {
            int mid = (lo + hi) >> 1;
            if (gids[mid] < g) lo = mid + 1; else hi = mid;
        }
        gstart[g] = lo;
    }
    // W23 = W2 @ W3  [32,2]
    if (tid < HIDDEN * 2) {
        int r = tid >> 1, o = tid & 1;
        float s = 0.f;
        for (int k = 0; k < HIDDEN; k++) s += W2[r * HIDDEN + k] * W3[k * 2 + o];
        w23[tid] = s;
    }
    __syncthreads();
    // M = W1 @ W23  [64,2]
    if (tid < IN_FEATS * 2) {
        int r = tid >> 1, o = tid & 1;
        float s = 0.f;
        for (int k = 0; k < HIDDEN; k++) s += W1[r * HIDDEN + k] * w23[k * 2 + o];
        Mg[tid] = s;
    }
    // c1 = b1 @ W23 ; c2 = b2 @ W3 ; czero
    if (tid < 2) {
        float s1 = 0.f, s2 = 0.f;
        for (int k = 0; k < HIDDEN; k++) {
            s1 += b1[k] * w23[k * 2 + tid];
            s2 += b2[k] * W3[k * 2 + tid];
        }
        cc[tid] = s1;        // c1
        cc[2 + tid] = s2;    // c2
        cc[4 + tid] = 0.f;   // czero
    }
}

// ---------------- K1: per-graph mean + fused prediction (R8-proven) ----------------
__global__ __launch_bounds__(256) void k_gsum2(const float* __restrict__ nf,
                                               const int* __restrict__ gids,
                                               const int* __restrict__ gstart,
                                               float* __restrict__ ge, int N,
                                               int nblocks, int* __restrict__ done,
                                               const float* __restrict__ Wl,
                                               const float* __restrict__ bl,
                                               float* __restrict__ out) {
    int c0 = blockIdx.x * GCH;
    int c1 = c0 + GCH; if (c1 > N) c1 = N;
    int tid = threadIdx.x;
    int ng = tid >> 4;    // node group 0..15
    int f4 = tid & 15;    // float4 column

    if (c0 < N) {
        int gfirst = gids[c0];
        int glast  = gids[c1 - 1];
        __shared__ float4 red[256];
        for (int g = gfirst; g <= glast; g++) {
            int s = gstart[g];     if (s < c0) s = c0;
            int e = gstart[g + 1]; if (e > c1) e = c1;
            float4 acc = make_float4(0.f, 0.f, 0.f, 0.f);
            for (int i = s + ng; i < e; i += 16) {
                float4 v = *reinterpret_cast<const float4*>(nf + (long long)i * IN_FEATS + f4 * 4);
                acc.x += v.x; acc.y += v.y; acc.z += v.z; acc.w += v.w;
            }
            red[tid] = acc;
            __syncthreads();
            for (int off = 8; off > 0; off >>= 1) {
                if (ng < off) {
                    float4 o = red[(ng + off) * 16 + f4];
                    float4 m = red[tid];
                    m.x += o.x; m.y += o.y; m.z += o.z; m.w += o.w;
                    red[tid] = m;
                }
                __syncthreads();
            }
            if (ng == 0 && e > s) {
                float4 m = red[f4];
                atomicAdd(&ge[g * IN_FEATS + f4 * 4 + 0], m.x);
                atomicAdd(&ge[g * IN_FEATS + f4 * 4 + 1], m.y);
                atomicAdd(&ge[g * IN_FEATS + f4 * 4 + 2], m.z);
                atomicAdd(&ge[g * IN_FEATS + f4 * 4 + 3], m.w);
            }
            __syncthreads();
        }
    }
    __threadfence();
    __shared__ int isLast;
    if (tid == 0) isLast = (atomicAdd(&done[1], 1) == nblocks - 1) ? 1 : 0;
    __syncthreads();
    if (isLast) {
        __threadfence();
        int g = tid;
        if (g < N_GRAPHS) {
            float cnt = (float)(gstart[g + 1] - gstart[g]);
            float inv = 1.f / fmaxf(cnt, 1.0f);
            float acc = 0.f;
            for (int k = 0; k < IN_FEATS; k++)
                acc += ge[g * IN_FEATS + k] * Wl[k];
            acc = acc * inv + bl[0];
            out[g] = 1.f / (1.f + expf(-acc));
        }
    }
}

// ---------------- K2: y0 = X @ M  [N,2]; also zero t1..t3 (scatter targets) ----------------
__global__ __launch_bounds__(256) void k_y0(const float* __restrict__ nf,
                                            const float* __restrict__ Mg,
                                            float* __restrict__ y0,
                                            float* __restrict__ zbase,
                                            int N) {
    __shared__ float2 Ms[IN_FEATS];
    int tid = threadIdx.x;
    if (tid < IN_FEATS) Ms[tid] = reinterpret_cast<const float2*>(Mg)[tid];
    __syncthreads();

    // zero t1..t3 (3 * N * 2 floats), grid-stride
    int total = 3 * N * 2;
    int stride = gridDim.x * 256;
    for (int i = blockIdx.x * 256 + tid; i < total; i += stride) zbase[i] = 0.f;

    int row = blockIdx.x * 256 + tid;
    if (row >= N) return;
    const float4* r4 = reinterpret_cast<const float4*>(nf + (long long)row * IN_FEATS);
    float a0 = 0.f, a1 = 0.f;
    #pragma unroll
    for (int v = 0; v < IN_FEATS / 4; v++) {
        float4 q = r4[v];
        float2 m0 = Ms[4 * v + 0], m1 = Ms[4 * v + 1];
        float2 m2 = Ms[4 * v + 2], m3 = Ms[4 * v + 3];
        a0 += q.x * m0.x + q.y * m1.x + q.z * m2.x + q.w * m3.x;
        a1 += q.x * m0.y + q.y * m1.y + q.z * m2.y + q.w * m3.y;
    }
    reinterpret_cast<float2*>(y0)[row] = make_float2(a0, a1);
}

// ---------------- K3/K4/K5: edge-parallel scatter-add, 2 feats ----------------
// tout[dst] += tin[src] + cadd   (cadd folds the previous layer's bias; isolated
// nodes correctly stay 0 because the constant rides on the *read* side)
__global__ __launch_bounds__(256) void k_sc2(const int* __restrict__ src,
                                             const int* __restrict__ dst,
                                             const float* __restrict__ tin,
                                             float* __restrict__ tout,
                                             const float* __restrict__ cadd,
                                             int E) {
    int e = blockIdx.x * 256 + threadIdx.x;
    if (e >= E) return;
    int s = src[e], d = dst[e];
    float2 v = reinterpret_cast<const float2*>(tin)[s];
    float cx = cadd[0], cy = cadd[1];
    atomicAdd(&tout[2 * d + 0], v.x + cx);
    atomicAdd(&tout[2 * d + 1], v.y + cy);
}

// ---------------- K6: h3 = t3 + b3 -> d_out ----------------
__global__ void k_fin(const float* __restrict__ t3,
                      const float* __restrict__ b3,
                      float* __restrict__ out, int n2) {
    int i = blockIdx.x * 256 + threadIdx.x;
    if (i < n2) out[i] = t3[i] + b3[i & 1];
}

extern "C" void kernel_launch(void* const* d_in, const int* in_sizes, int n_in,
                              void* d_out, int out_size, void* d_ws, size_t ws_size,
                              hipStream_t stream) {
    const float* nf = (const float*)d_in[0];   // node_feats f32 [N,64]
    const float* W1 = (const float*)d_in[2];   // [64,32]
    const float* b1 = (const float*)d_in[3];   // [32]
    const float* W2 = (const float*)d_in[4];   // [32,32]
    const float* b2 = (const float*)d_in[5];   // [32]
    const float* W3 = (const float*)d_in[6];   // [32,2]
    const float* b3 = (const float*)d_in[7];   // [2]
    const float* Wl = (const float*)d_in[8];   // [64,1]
    const float* bl = (const float*)d_in[9];   // [1]
    const int* src  = (const int*)d_in[10];
    const int* dst  = (const int*)d_in[11];
    const int* gids = (const int*)d_in[12];

    const int N = in_sizes[0] / IN_FEATS;     // 100000
    const int E = in_sizes[10];               // 1600000

    float* out = (float*)d_out;

    // workspace (all f32): y0 | t1 | t2 | t3 | M | cc | ge | gstart | done
    float* y0 = (float*)d_ws;                 // [N,2]
    float* t1 = y0 + (size_t)N * 2;           // [N,2]
    float* t2 = t1 + (size_t)N * 2;           // [N,2]
    float* t3 = t2 + (size_t)N * 2;           // [N,2]
    float* Mg = t3 + (size_t)N * 2;           // [64,2]
    float* cc = Mg + IN_FEATS * 2;            // [6] : c1(2), c2(2), czero(2)
    float* ge = cc + 8;                       // [64,64]
    int* gstart = (int*)(ge + N_GRAPHS * IN_FEATS); // [65]
    int* done = gstart + N_GRAPHS + 1;        // [2]

    const int TB = 256;
    int nodeBlocks = (N + TB - 1) / TB;       // 391
    int edgeBlocks = (E + TB - 1) / TB;       // 6250
    int finBlocks = (N * 2 + TB - 1) / TB;    // 782

    // K0: bounds + zeros + M/c1/c2
    k_init<<<1, TB, 0, stream>>>(gids, N, gstart, ge, done, W1, b1, W2, b2, W3, Mg, cc);

    // K1: per-graph mean + prediction (independent branch)
    k_gsum2<<<nodeBlocks, TB, 0, stream>>>(nf, gids, gstart, ge, N,
                                           nodeBlocks, done, Wl, bl, out);

    // K2: y0 = X@M, zero t1..t3
    k_y0<<<nodeBlocks, TB, 0, stream>>>(nf, Mg, y0, t1, N);

    // K3..K5: three 2-wide scatter-adds (the entire GCN chain)
    k_sc2<<<edgeBlocks, TB, 0, stream>>>(src, dst, y0, t1, cc + 4, E);  // t1 = A·y0
    k_sc2<<<edgeBlocks, TB, 0, stream>>>(src, dst, t1, t2, cc + 0, E);  // t2 = A·(t1+c1)
    k_sc2<<<edgeBlocks, TB, 0, stream>>>(src, dst, t2, t3, cc + 2, E);  // t3 = A·(t2+c2)

    // K6: h3 = t3 + b3
    k_fin<<<finBlocks, TB, 0, stream>>>(t3, b3, out + N_GRAPHS, N * 2);
}

// Round 12
// 344.435 us; speedup vs baseline: 2.0772x; 2.0772x over previous
//
#include <hip/hip_runtime.h>

#define N_GRAPHS 64
#define IN_FEATS 64
#define HIDDEN 32

#define NB 512        // dst-range buckets
#define PCH 8192      // edges per partition block (LDS stage = 32 KB packed)
#define GCH 256       // nodes per gsum chunk

// ---------------- K0: init ----------------
// graph bounds, ge zero, done zero, M = W1@W2@W3 [64,2], c1 = b1@W2@W3, c2 = b2@W3
__global__ __launch_bounds__(256) void k_init(const int* __restrict__ gids, int n,
                                              int* __restrict__ gstart,
                                              float* __restrict__ ge,
                                              int* __restrict__ gcount,
                                              int* __restrict__ done,
                                              const float* __restrict__ W1,
                                              const float* __restrict__ b1,
                                              const float* __restrict__ W2,
                                              const float* __restrict__ b2,
                                              const float* __restrict__ W3,
                                              float* __restrict__ Mg,
                                              float* __restrict__ cc) {
    __shared__ float w23[HIDDEN * 2];
    int tid = threadIdx.x;
    for (int i = tid; i < N_GRAPHS * IN_FEATS; i += 256) ge[i] = 0.f;
    for (int i = tid; i < NB; i += 256) gcount[i] = 0;
    if (tid < 2) done[tid] = 0;
    if (tid <= N_GRAPHS) {
        int g = tid;
        int lo = 0, hi = n;
        while (lo < hi) {
            int mid = (lo + hi) >> 1;
            if (gids[mid] < g) lo = mid + 1; else hi = mid;
        }
        gstart[g] = lo;
    }
    // W23 = W2 @ W3  [32,2]
    if (tid < HIDDEN * 2) {
        int r = tid >> 1, o = tid & 1;
        float s = 0.f;
        for (int k = 0; k < HIDDEN; k++) s += W2[r * HIDDEN + k] * W3[k * 2 + o];
        w23[tid] = s;
    }
    __syncthreads();
    // M = W1 @ W23  [64,2]
    if (tid < IN_FEATS * 2) {
        int r = tid >> 1, o = tid & 1;
        float s = 0.f;
        for (int k = 0; k < HIDDEN; k++) s += W1[r * HIDDEN + k] * w23[k * 2 + o];
        Mg[tid] = s;
    }
    // c1 = b1 @ W23 ; c2 = b2 @ W3
    if (tid < 2) {
        float s1 = 0.f, s2 = 0.f;
        for (int k = 0; k < HIDDEN; k++) {
            s1 += b1[k] * w23[k * 2 + tid];
            s2 += b2[k] * W3[k * 2 + tid];
        }
        cc[tid] = 0.f;       // c for hop 1 (none)
        cc[2 + tid] = s1;    // c1 for hop 2
        cc[4 + tid] = s2;    // c2 for hop 3
    }
}

// ---------------- K1: per-graph mean + fused prediction (R8-proven) ----------------
__global__ __launch_bounds__(256) void k_gsum2(const float* __restrict__ nf,
                                               const int* __restrict__ gids,
                                               const int* __restrict__ gstart,
                                               float* __restrict__ ge, int N,
                                               int nblocks, int* __restrict__ done,
                                               const float* __restrict__ Wl,
                                               const float* __restrict__ bl,
                                               float* __restrict__ out) {
    int c0 = blockIdx.x * GCH;
    int c1 = c0 + GCH; if (c1 > N) c1 = N;
    int tid = threadIdx.x;
    int ng = tid >> 4;
    int f4 = tid & 15;

    if (c0 < N) {
        int gfirst = gids[c0];
        int glast  = gids[c1 - 1];
        __shared__ float4 red[256];
        for (int g = gfirst; g <= glast; g++) {
            int s = gstart[g];     if (s < c0) s = c0;
            int e = gstart[g + 1]; if (e > c1) e = c1;
            float4 acc = make_float4(0.f, 0.f, 0.f, 0.f);
            for (int i = s + ng; i < e; i += 16) {
                float4 v = *reinterpret_cast<const float4*>(nf + (long long)i * IN_FEATS + f4 * 4);
                acc.x += v.x; acc.y += v.y; acc.z += v.z; acc.w += v.w;
            }
            red[tid] = acc;
            __syncthreads();
            for (int off = 8; off > 0; off >>= 1) {
                if (ng < off) {
                    float4 o = red[(ng + off) * 16 + f4];
                    float4 m = red[tid];
                    m.x += o.x; m.y += o.y; m.z += o.z; m.w += o.w;
                    red[tid] = m;
                }
                __syncthreads();
            }
            if (ng == 0 && e > s) {
                float4 m = red[f4];
                atomicAdd(&ge[g * IN_FEATS + f4 * 4 + 0], m.x);
                atomicAdd(&ge[g * IN_FEATS + f4 * 4 + 1], m.y);
                atomicAdd(&ge[g * IN_FEATS + f4 * 4 + 2], m.z);
                atomicAdd(&ge[g * IN_FEATS + f4 * 4 + 3], m.w);
            }
            __syncthreads();
        }
    }
    __threadfence();
    __shared__ int isLast;
    if (tid == 0) isLast = (atomicAdd(&done[1], 1) == nblocks - 1) ? 1 : 0;
    __syncthreads();
    if (isLast) {
        __threadfence();
        int g = tid;
        if (g < N_GRAPHS) {
            float cnt = (float)(gstart[g + 1] - gstart[g]);
            float inv = 1.f / fmaxf(cnt, 1.0f);
            float acc = 0.f;
            for (int k = 0; k < IN_FEATS; k++)
                acc += ge[g * IN_FEATS + k] * Wl[k];
            acc = acc * inv + bl[0];
            out[g] = 1.f / (1.f + expf(-acc));
        }
    }
}

// ---------------- K2: y0 = X @ M  [N,2] ----------------
__global__ __launch_bounds__(256) void k_y0(const float* __restrict__ nf,
                                            const float* __restrict__ Mg,
                                            float* __restrict__ y0, int N) {
    __shared__ float2 Ms[IN_FEATS];
    int tid = threadIdx.x;
    if (tid < IN_FEATS) Ms[tid] = reinterpret_cast<const float2*>(Mg)[tid];
    __syncthreads();
    int row = blockIdx.x * 256 + tid;
    if (row >= N) return;
    const float4* r4 = reinterpret_cast<const float4*>(nf + (long long)row * IN_FEATS);
    float a0 = 0.f, a1 = 0.f;
    #pragma unroll
    for (int v = 0; v < IN_FEATS / 4; v++) {
        float4 q = r4[v];
        float2 m0 = Ms[4 * v + 0], m1 = Ms[4 * v + 1];
        float2 m2 = Ms[4 * v + 2], m3 = Ms[4 * v + 3];
        a0 += q.x * m0.x + q.y * m1.x + q.z * m2.x + q.w * m3.x;
        a1 += q.x * m0.y + q.y * m1.y + q.z * m2.y + q.w * m3.y;
    }
    reinterpret_cast<float2*>(y0)[row] = make_float2(a0, a1);
}

// ---------------- CSR build (R6-proven) ----------------

__global__ __launch_bounds__(256) void k_hist(const int* __restrict__ dst,
                                              int* __restrict__ gcount,
                                              int E, int nb_sz) {
    __shared__ int lc[NB];
    for (int k = threadIdx.x; k < NB; k += 256) lc[k] = 0;
    __syncthreads();
    int stride = gridDim.x * 256;
    for (int i = blockIdx.x * 256 + threadIdx.x; i < E; i += stride)
        atomicAdd(&lc[dst[i] / nb_sz], 1);
    __syncthreads();
    for (int k = threadIdx.x; k < NB; k += 256)
        if (lc[k]) atomicAdd(&gcount[k], lc[k]);
}

__global__ __launch_bounds__(256) void k_scan512(const int* __restrict__ gcount,
                                                 int* __restrict__ gbase,
                                                 int* __restrict__ gcur, int E) {
    __shared__ int sA[NB], sB[NB];
    int tid = threadIdx.x;
    int c0 = gcount[tid], c1 = gcount[tid + 256];
    sA[tid] = c0; sA[tid + 256] = c1;
    __syncthreads();
    int* a = sA; int* bb = sB;
    for (int off = 1; off < NB; off <<= 1) {
        for (int k = tid; k < NB; k += 256) {
            int v = a[k];
            if (k >= off) v += a[k - off];
            bb[k] = v;
        }
        __syncthreads();
        int* t_ = a; a = bb; bb = t_;
    }
    int e0 = a[tid] - c0, e1 = a[tid + 256] - c1;
    gbase[tid] = e0;       gbase[tid + 256] = e1;
    gcur[tid] = e0;        gcur[tid + 256] = e1;
    if (tid == 0) gbase[NB] = E;
}

// packed pair: (src << 8) | (dst - bucket_base); nb_sz<=256
__global__ __launch_bounds__(256) void k_partition(const int* __restrict__ src,
                                                   const int* __restrict__ dst,
                                                   int* __restrict__ gcur,
                                                   unsigned int* __restrict__ pairs,
                                                   int E, int nb_sz) {
    __shared__ unsigned int stage[PCH];
    __shared__ int sA[NB], sB[NB], ofs[NB + 1], cur[NB], rbase[NB];
    int tid = threadIdx.x;
    int e0 = blockIdx.x * PCH;
    int m = E - e0; if (m > PCH) m = PCH;

    for (int k = tid; k < NB; k += 256) sA[k] = 0;
    __syncthreads();
    for (int i = tid; i < m; i += 256)
        atomicAdd(&sA[dst[e0 + i] / nb_sz], 1);
    __syncthreads();
    int c0 = sA[tid], c1 = sA[tid + 256];
    int* a = sA; int* bb = sB;
    for (int off = 1; off < NB; off <<= 1) {
        for (int k = tid; k < NB; k += 256) {
            int v = a[k];
            if (k >= off) v += a[k - off];
            bb[k] = v;
        }
        __syncthreads();
        int* t_ = a; a = bb; bb = t_;
    }
    int x0 = a[tid] - c0, x1 = a[tid + 256] - c1;
    ofs[tid] = x0;       ofs[tid + 256] = x1;
    cur[tid] = x0;       cur[tid + 256] = x1;
    if (tid == 0) ofs[NB] = m;
    __syncthreads();
    for (int i = tid; i < m; i += 256) {
        int d = dst[e0 + i];
        int s = src[e0 + i];
        int b = d / nb_sz;
        int p = atomicAdd(&cur[b], 1);
        stage[p] = ((unsigned)s << 8) | (unsigned)(d - b * nb_sz);
    }
    __syncthreads();
    for (int k = tid; k < NB; k += 256) {
        int cnt = ofs[k + 1] - ofs[k];
        rbase[k] = cnt > 0 ? atomicAdd(&gcur[k], cnt) : 0;
    }
    __syncthreads();
    for (int i = tid; i < m; i += 256) {
        int lo = 0, hi = NB;
        while (hi - lo > 1) {
            int mid = (lo + hi) >> 1;
            if (ofs[mid] <= i) lo = mid; else hi = mid;
        }
        pairs[rbase[lo] + (i - ofs[lo])] = stage[i];
    }
}

__global__ __launch_bounds__(256) void k_csr_local(const unsigned int* __restrict__ pairs,
                                                   const int* __restrict__ gbase,
                                                   int* __restrict__ csr,
                                                   int* __restrict__ ptr,
                                                   int N, int nb_sz) {
    int b = blockIdx.x;
    int n0 = b * nb_sz;
    if (n0 >= N) return;
    int n1 = n0 + nb_sz; if (n1 > N) n1 = N;
    int nn = n1 - n0;

    __shared__ int cnt[256], scn[256], cur[256];
    int tid = threadIdx.x;
    cnt[tid] = 0;
    __syncthreads();
    int s = gbase[b], e = gbase[b + 1];
    for (int i = s + tid; i < e; i += 256)
        atomicAdd(&cnt[pairs[i] & 0xFFu], 1);
    __syncthreads();
    int c = cnt[tid];
    scn[tid] = c;
    __syncthreads();
    for (int off = 1; off < 256; off <<= 1) {
        int mine = scn[tid];
        int add = (tid >= off) ? scn[tid - off] : 0;
        __syncthreads();
        scn[tid] = mine + add;
        __syncthreads();
    }
    cur[tid] = scn[tid] - c;
    if (tid < nn) ptr[n0 + tid] = s + scn[tid];   // end offset
    __syncthreads();
    for (int i = s + tid; i < e; i += 256) {
        unsigned int p = pairs[i];
        int pos = atomicAdd(&cur[p & 0xFFu], 1);
        csr[s + pos] = (int)(p >> 8);
    }
}

// ---------------- hop gathers: tout[n] = sum_{s in in(n)} tin[s] + deg*c ----------------

__global__ __launch_bounds__(256) void k_gather2(const float* __restrict__ tin,
                                                 const int* __restrict__ csr,
                                                 const int* __restrict__ ptr,
                                                 const float* __restrict__ cadd,
                                                 float* __restrict__ tout, int n) {
    int node = blockIdx.x * 256 + threadIdx.x;
    if (node >= n) return;
    int start = node ? ptr[node - 1] : 0;
    int end = ptr[node];
    float a0 = 0.f, a1 = 0.f;
    int j = start;
    for (; j + 3 < end; j += 4) {
        int s0 = csr[j], s1 = csr[j + 1], s2 = csr[j + 2], s3 = csr[j + 3];
        float2 v0 = reinterpret_cast<const float2*>(tin)[s0];
        float2 v1 = reinterpret_cast<const float2*>(tin)[s1];
        float2 v2 = reinterpret_cast<const float2*>(tin)[s2];
        float2 v3 = reinterpret_cast<const float2*>(tin)[s3];
        a0 += v0.x + v1.x + v2.x + v3.x;
        a1 += v0.y + v1.y + v2.y + v3.y;
    }
    for (; j < end; j++) {
        float2 v = reinterpret_cast<const float2*>(tin)[csr[j]];
        a0 += v.x; a1 += v.y;
    }
    float deg = (float)(end - start);
    reinterpret_cast<float2*>(tout)[node] = make_float2(a0 + deg * cadd[0], a1 + deg * cadd[1]);
}

// hop 3 fused with +b3, straight into d_out
__global__ __launch_bounds__(256) void k_gather2_out(const float* __restrict__ tin,
                                                     const int* __restrict__ csr,
                                                     const int* __restrict__ ptr,
                                                     const float* __restrict__ cadd,
                                                     const float* __restrict__ b3,
                                                     float* __restrict__ out, int n) {
    int node = blockIdx.x * 256 + threadIdx.x;
    if (node >= n) return;
    int start = node ? ptr[node - 1] : 0;
    int end = ptr[node];
    float a0 = 0.f, a1 = 0.f;
    int j = start;
    for (; j + 3 < end; j += 4) {
        int s0 = csr[j], s1 = csr[j + 1], s2 = csr[j + 2], s3 = csr[j + 3];
        float2 v0 = reinterpret_cast<const float2*>(tin)[s0];
        float2 v1 = reinterpret_cast<const float2*>(tin)[s1];
        float2 v2 = reinterpret_cast<const float2*>(tin)[s2];
        float2 v3 = reinterpret_cast<const float2*>(tin)[s3];
        a0 += v0.x + v1.x + v2.x + v3.x;
        a1 += v0.y + v1.y + v2.y + v3.y;
    }
    for (; j < end; j++) {
        float2 v = reinterpret_cast<const float2*>(tin)[csr[j]];
        a0 += v.x; a1 += v.y;
    }
    float deg = (float)(end - start);
    reinterpret_cast<float2*>(out)[node] =
        make_float2(a0 + deg * cadd[0] + b3[0], a1 + deg * cadd[1] + b3[1]);
}

extern "C" void kernel_launch(void* const* d_in, const int* in_sizes, int n_in,
                              void* d_out, int out_size, void* d_ws, size_t ws_size,
                              hipStream_t stream) {
    const float* nf = (const float*)d_in[0];   // node_feats f32 [N,64]
    const float* W1 = (const float*)d_in[2];   // [64,32]
    const float* b1 = (const float*)d_in[3];   // [32]
    const float* W2 = (const float*)d_in[4];   // [32,32]
    const float* b2 = (const float*)d_in[5];   // [32]
    const float* W3 = (const float*)d_in[6];   // [32,2]
    const float* b3 = (const float*)d_in[7];   // [2]
    const float* Wl = (const float*)d_in[8];   // [64,1]
    const float* bl = (const float*)d_in[9];   // [1]
    const int* src  = (const int*)d_in[10];
    const int* dst  = (const int*)d_in[11];
    const int* gids = (const int*)d_in[12];

    const int N = in_sizes[0] / IN_FEATS;     // 100000
    const int E = in_sizes[10];               // 1600000
    const int nb_sz = (N + NB - 1) / NB;      // 196 (<=256 required for packing)

    float* out = (float*)d_out;

    // workspace: y0/t [N,2] ×2 ping-pong | pairs [E] | csr [E] | ptr [N] | small
    float* yA = (float*)d_ws;                 // [N,2]
    float* yB = yA + (size_t)N * 2;           // [N,2]
    unsigned int* pairs = (unsigned int*)(yB + (size_t)N * 2); // [E]
    int* csr     = (int*)(pairs + E);         // [E]
    int* ptr     = csr + E;                   // [N]
    int* gcount  = ptr + N;                   // [NB]
    int* gbase   = gcount + NB;               // [NB+1]
    int* gcur    = gbase + NB + 1;            // [NB]
    float* Mg    = (float*)(gcur + NB);       // [64,2]
    float* cc    = Mg + IN_FEATS * 2;         // [6]
    float* ge    = cc + 8;                    // [64,64]
    int* gstart  = (int*)(ge + N_GRAPHS * IN_FEATS); // [65]
    int* done    = gstart + N_GRAPHS + 1;     // [2]

    const int TB = 256;
    int nodeBlocks = (N + TB - 1) / TB;       // 391
    int partBlocks = (E + PCH - 1) / PCH;

    // K0: bounds + zeros + folded weights
    k_init<<<1, TB, 0, stream>>>(gids, N, gstart, ge, gcount, done,
                                 W1, b1, W2, b2, W3, Mg, cc);

    // K1: per-graph mean + prediction (independent branch)
    k_gsum2<<<nodeBlocks, TB, 0, stream>>>(nf, gids, gstart, ge, N,
                                           nodeBlocks, done, Wl, bl, out);

    // K2: y0 = X@M
    k_y0<<<nodeBlocks, TB, 0, stream>>>(nf, Mg, yA, N);

    // K3..K6: CSR build
    k_hist<<<256, TB, 0, stream>>>(dst, gcount, E, nb_sz);
    k_scan512<<<1, TB, 0, stream>>>(gcount, gbase, gcur, E);
    k_partition<<<partBlocks, TB, 0, stream>>>(src, dst, gcur, pairs, E, nb_sz);
    k_csr_local<<<NB, TB, 0, stream>>>(pairs, gbase, csr, ptr, N, nb_sz);

    // K7..K9: three 2-wide hops (atomic-free gathers; constants folded via deg)
    k_gather2<<<nodeBlocks, TB, 0, stream>>>(yA, csr, ptr, cc + 0, yB, N);       // hop1
    k_gather2<<<nodeBlocks, TB, 0, stream>>>(yB, csr, ptr, cc + 2, yA, N);       // hop2 (+c1)
    k_gather2_out<<<nodeBlocks, TB, 0, stream>>>(yA, csr, ptr, cc + 4, b3,
                                                 out + N_GRAPHS, N);             // hop3 (+c2,+b3)
}